// Round 3
// baseline (642.822 us; speedup 1.0000x reference)
//
#include <hip/hip_runtime.h>
#include <hip/hip_bf16.h>

#define IN_CH 256
#define HID 16

typedef __attribute__((ext_vector_type(8))) short bf16x8;
typedef __attribute__((ext_vector_type(4))) float floatx4;

static __device__ __forceinline__ short f2bf(float f) {
    __hip_bfloat16 h = __float2bfloat16(f);   // round-to-nearest-even
    return *reinterpret_cast<short*>(&h);
}

// ---------------- degree count ----------------
__global__ void k_deg(const int* __restrict__ tgt, int* __restrict__ deg, int E) {
    int e = blockIdx.x * blockDim.x + threadIdx.x;
    if (e < E) atomicAdd(&deg[tgt[e]], 1);
}

// ---------------- deg^{-1/2} ----------------
__global__ void k_dis(const int* __restrict__ deg, float* __restrict__ dis, int N) {
    int n = blockIdx.x * blockDim.x + threadIdx.x;
    if (n < N) {
        int d = deg[n];
        dis[n] = (d > 0) ? rsqrtf((float)d) : 0.0f;
    }
}

// ---------------- layer-1 GEMM: h1[n][c] = dis[n] * (x[n]@W1[:,c] + b1[c]) ----------------
// x, W1 are f32; converted to bf16 on the fly for mfma_f32_16x16x32_bf16.
// One wave per 16-node tile, K=256 -> 8 MFMAs.
// A layout: A[m=lane&15][k=(lane>>4)*8+j]; B: B[k=(lane>>4)*8+j][n=lane&15]
// C/D: col=lane&15 (channel), row=(lane>>4)*4+r (node in tile)
__global__ void k_gemm1(const float* __restrict__ x,
                        const float* __restrict__ W1,
                        const float* __restrict__ b1,
                        const float* __restrict__ dis,
                        float* __restrict__ h1, int N) {
    int lane = threadIdx.x & 63;
    int wave = threadIdx.x >> 6;
    int tile = blockIdx.x * 4 + wave;
    int nb = tile * 16;
    if (nb >= N) return;

    int mc = lane & 15;   // A row (node) index AND B col (channel) index
    int q  = lane >> 4;   // quad

    // W1 fragments (W1 is 16 KB f32, uniform across waves -> L1-resident)
    bf16x8 bfrag[8];
#pragma unroll
    for (int kb = 0; kb < 8; kb++) {
#pragma unroll
        for (int j = 0; j < 8; j++) {
            bfrag[kb][j] = f2bf(W1[(kb * 32 + q * 8 + j) * HID + mc]);
        }
    }

    const float* xrow = x + (size_t)(nb + mc) * IN_CH;
    floatx4 acc = {0.f, 0.f, 0.f, 0.f};
#pragma unroll
    for (int kb = 0; kb < 8; kb++) {
        const floatx4* p = (const floatx4*)(xrow + kb * 32 + q * 8);
        floatx4 v0 = p[0];
        floatx4 v1 = p[1];
        bf16x8 afrag;
#pragma unroll
        for (int j = 0; j < 4; j++) {
            afrag[j]     = f2bf(v0[j]);
            afrag[j + 4] = f2bf(v1[j]);
        }
        acc = __builtin_amdgcn_mfma_f32_16x16x32_bf16(afrag, bfrag[kb], acc, 0, 0, 0);
    }

    float bias = b1[mc];  // channel = lane&15
#pragma unroll
    for (int r = 0; r < 4; r++) {
        int node = nb + q * 4 + r;
        if (node < N) {
            h1[(size_t)node * HID + mc] = (acc[r] + bias) * dis[node];
        }
    }
}

// ---------------- gather + scatter-add (norm factored out) ----------------
// agg[t][c] += h[s][c];  h pre-scaled by dis[s]; dis[t] applied downstream.
__global__ void k_scatter(const int* __restrict__ src, const int* __restrict__ tgt,
                          const float* __restrict__ h, float* __restrict__ agg, int E) {
    int g = blockIdx.x * blockDim.x + threadIdx.x;
    if (g >= E * HID) return;
    int e = g >> 4;
    int c = g & 15;
    int s = src[e];
    int t = tgt[e];
    atomicAdd(&agg[(size_t)t * HID + c], h[(size_t)s * HID + c]);
}

// ---------------- h2 = dis * (sigmoid(dis*agg1) @ W2 + b2) ----------------
__global__ void k_mid(const float* __restrict__ agg1,
                      const float* __restrict__ W2,
                      const float* __restrict__ b2,
                      const float* __restrict__ dis,
                      float* __restrict__ h2, int N) {
    __shared__ float w2s[HID * HID];
    __shared__ float b2s[HID];
    int t = threadIdx.x;
    if (t < HID * HID) w2s[t] = W2[t];
    if (t < HID)       b2s[t] = b2[t];
    __syncthreads();

    int n = blockIdx.x * blockDim.x + t;
    if (n >= N) return;
    float d = dis[n];

    float hs[HID];
#pragma unroll
    for (int c = 0; c < HID; c++) {
        float v = d * agg1[(size_t)n * HID + c];
        hs[c] = 1.0f / (1.0f + __expf(-v));
    }
    float acc[HID];
#pragma unroll
    for (int c2 = 0; c2 < HID; c2++) acc[c2] = b2s[c2];
#pragma unroll
    for (int c = 0; c < HID; c++) {
#pragma unroll
        for (int c2 = 0; c2 < HID; c2++) {
            acc[c2] += hs[c] * w2s[c * HID + c2];
        }
    }
#pragma unroll
    for (int c2 = 0; c2 < HID; c2++) {
        h2[(size_t)n * HID + c2] = acc[c2] * d;
    }
}

// ---------------- final: out = sigmoid(dis[t]*agg2), f32 output ----------------
__global__ void k_out(const float* __restrict__ agg2, const float* __restrict__ dis,
                      float* __restrict__ out, int N) {
    int g = blockIdx.x * blockDim.x + threadIdx.x;
    if (g >= N * HID) return;
    int n = g >> 4;
    float v = dis[n] * agg2[g];
    out[g] = 1.0f / (1.0f + __expf(-v));
}

extern "C" void kernel_launch(void* const* d_in, const int* in_sizes, int n_in,
                              void* d_out, int out_size, void* d_ws, size_t ws_size,
                              hipStream_t stream) {
    const float* x  = (const float*)d_in[0];
    const int*   ei = (const int*)d_in[1];
    const float* W1 = (const float*)d_in[2];
    const float* b1 = (const float*)d_in[3];
    const float* W2 = (const float*)d_in[4];
    const float* b2 = (const float*)d_in[5];
    float* out = (float*)d_out;   // reference output dtype is float32

    int N = in_sizes[0] / IN_CH;   // 100000
    int E = in_sizes[1] / 2;       // 3200000
    const int* src = ei;
    const int* tgt = ei + E;

    // workspace: [deg int N][agg1 f32 16N][agg2 f32 16N][dis f32 N][h1 f32 16N][h2 f32 16N]
    char* ws = (char*)d_ws;
    auto align256 = [](size_t v) { return (v + 255) & ~(size_t)255; };
    size_t off = 0;
    int*   deg  = (int*)(ws + off);   off += align256((size_t)N * sizeof(int));
    float* agg1 = (float*)(ws + off); off += align256((size_t)N * HID * sizeof(float));
    float* agg2 = (float*)(ws + off); off += align256((size_t)N * HID * sizeof(float));
    size_t zero_bytes = off;
    float* dis  = (float*)(ws + off); off += align256((size_t)N * sizeof(float));
    float* h1   = (float*)(ws + off); off += align256((size_t)N * HID * sizeof(float));
    float* h2   = (float*)(ws + off); off += align256((size_t)N * HID * sizeof(float));

    hipMemsetAsync(ws, 0, zero_bytes, stream);

    const int B = 256;
    int grid_deg  = (E + B - 1) / B;
    int grid_n    = (N + B - 1) / B;
    int grid_g1   = ((N + 15) / 16 + 3) / 4;   // one wave per 16-node tile, 4 waves/block
    int grid_sc   = (E * HID + B - 1) / B;
    int grid_out  = (N * HID + B - 1) / B;

    k_deg<<<grid_deg, B, 0, stream>>>(tgt, deg, E);
    k_dis<<<grid_n, B, 0, stream>>>(deg, dis, N);
    k_gemm1<<<grid_g1, B, 0, stream>>>(x, W1, b1, dis, h1, N);
    k_scatter<<<grid_sc, B, 0, stream>>>(src, tgt, h1, agg1, E);
    k_mid<<<grid_n, B, 0, stream>>>(agg1, W2, b2, dis, h2, N);
    k_scatter<<<grid_sc, B, 0, stream>>>(src, tgt, h2, agg2, E);
    k_out<<<grid_out, B, 0, stream>>>(agg2, dis, out, N);
}